// Round 9
// baseline (148.785 us; speedup 1.0000x reference)
//
#include <hip/hip_runtime.h>
#include <hip/hip_fp16.h>
#include <math.h>

#define BDIM 4
#define LDIM 512
#define EDIM 1024
#define HDIM 128
#define TILE 31            // interior y-tile per block (s-grid is 32x32 with 1 halo)
#define NT   17            // 17*31 = 527 >= 512 tiles per spatial dim
#define NTILES (NT * NT * BDIM)   // 1156 bilinear blocks
#define K2   2.885390081777927f   // 2/ln(2): tanh(x) = 1 - 2/(exp2(K2*x)+1)

typedef unsigned short ushort_t;
typedef __attribute__((ext_vector_type(8))) _Float16 half8;
typedef __attribute__((ext_vector_type(4))) float f32x4;

struct __align__(16) H8 { __half2 p[4]; };
union HU { H8 h; half8 v; };

__device__ __forceinline__ float sum_h2(__half2 v) {
  return __low2float(v) + __high2float(v);
}

// ---------------------------------------------------------------------------
// Kernel 0: W1 (1024x128 f32, k-major) -> Wt (128x1024 f16, n-major, k-contig)
// + zero the bilinear done-counter. 64 blocks.
// ---------------------------------------------------------------------------
__global__ __launch_bounds__(256) void cvt(const float* __restrict__ W1,
                                           ushort_t* __restrict__ Wt,
                                           unsigned* __restrict__ ctr) {
  if (blockIdx.x == 0 && threadIdx.x == 0) *ctr = 0u;
  const int g = (int)blockIdx.x * 256 + threadIdx.x;  // 0..16383
  const int n = g & 127, k8 = g >> 7;                 // k8: 0..127
  float v[8];
#pragma unroll
  for (int j = 0; j < 8; ++j) v[j] = W1[(size_t)(k8 * 8 + j) * HDIM + n];
  H8 o;
#pragma unroll
  for (int j = 0; j < 4; ++j) o.p[j] = __floats2half2_rn(v[2 * j], v[2 * j + 1]);
  *(H8*)&Wt[(size_t)n * EDIM + k8 * 8] = o;
}

// ---------------------------------------------------------------------------
// Kernel 1: hid = relu(emb @ W1 + b1) (* K2 on rec rows), f16 out, via f16
// MFMA 16x16x32. NO LDS / NO barriers / NO atomics: 2048 independent waves
// (512 blocks x 4); wave = 16-row strip x one 16-col frag x full K=1024.
// A-frag: 2x dwordx4 f32 + cvt; B-frag: one 16B load from Wt (k-contiguous,
// L2-hot). Compiler free to pipeline loads across chunks (unroll 8).
// ---------------------------------------------------------------------------
__global__ __launch_bounds__(256) void gemm_direct(
    const float* __restrict__ rec, const float* __restrict__ lig,
    const ushort_t* __restrict__ Wt, const float* __restrict__ b1,
    ushort_t* __restrict__ hid) {
  const int gw = (int)blockIdx.x * 4 + (threadIdx.x >> 6);  // 0..2047
  const int l = threadIdx.x & 63;
  const int strip = gw >> 3;          // 0..255 -> rows strip*16..+15
  const int nidx = gw & 7;            // col frag: cols nidx*16..+15
  const int r0 = strip * 16;
  const int m = l & 15, q = l >> 4;   // frag row, k-octet quad
  const float* arow = ((r0 < BDIM * LDIM)
                           ? rec + (size_t)r0 * EDIM
                           : lig + (size_t)(r0 - BDIM * LDIM) * EDIM) +
                      (size_t)m * EDIM + q * 8;
  const ushort_t* brow = Wt + (size_t)(nidx * 16 + m) * EDIM + q * 8;

  f32x4 acc = {0.f, 0.f, 0.f, 0.f};
#pragma unroll 8
  for (int c = 0; c < 32; ++c) {
    const int k0 = c * 32;
    float4 a_lo = *(const float4*)(arow + k0);
    float4 a_hi = *(const float4*)(arow + k0 + 4);
    HU au;
    au.h.p[0] = __floats2half2_rn(a_lo.x, a_lo.y);
    au.h.p[1] = __floats2half2_rn(a_lo.z, a_lo.w);
    au.h.p[2] = __floats2half2_rn(a_hi.x, a_hi.y);
    au.h.p[3] = __floats2half2_rn(a_hi.z, a_hi.w);
    half8 bf = *(const half8*)(brow + k0);
    acc = __builtin_amdgcn_mfma_f32_16x16x32_f16(au.v, bf, acc, 0, 0, 0);
  }

  // C/D: col(n-side) = lane&15, row(m-side) = (lane>>4)*4 + reg  [validated]
  const float scale = (r0 < BDIM * LDIM) ? K2 : 1.0f;
  const int col = nidx * 16 + m;
  const float bias = b1[col];
#pragma unroll
  for (int r = 0; r < 4; ++r) {
    float v = fmaxf(acc[r] + bias, 0.f) * scale;
    ((_Float16*)hid)[(size_t)(r0 + q * 4 + r) * HDIM + col] = (_Float16)v;
  }
}

// ---------------------------------------------------------------------------
// Kernel 2 (round-5 core, best measured @47.4us): per 31x31 y-tile:
// s_k(p,q) = Wsum_k + sum_h (-2 w_k[h]) * g(p,q,h), g = rcp(1+exp2(K2*r*l)).
// Tail: last-block finalize (device-scope counter) -> sigmoid -> out[0..3].
// ---------------------------------------------------------------------------
__global__ __launch_bounds__(256, 4) void bilinear_max(
    const ushort_t* __restrict__ hid, const float4* __restrict__ cw4,
    const float* __restrict__ cb, float* __restrict__ partial,
    unsigned* __restrict__ ctr, float* __restrict__ out) {
  __shared__ ushort_t rl[32][136];   // 272 B row stride
  __shared__ ushort_t ll[32][136];
  __shared__ __half whl[4][HDIM];    // -2*w_k[h] as f16, h-contiguous
  __shared__ float4 sl[32][33];      // f32 taps
  __shared__ float wred[4];
  __shared__ float4 wpart[2];
  __shared__ unsigned slast;

  const int t = threadIdx.x;
  const int b = blockIdx.z;
  const int ib = (int)blockIdx.y * TILE - 1;
  const int jb = (int)blockIdx.x * TILE - 1;

  if (t < HDIM) {
    float4 w4 = cw4[t];
    whl[0][t] = __float2half(-2.f * w4.x);
    whl[1][t] = __float2half(-2.f * w4.y);
    whl[2][t] = __float2half(-2.f * w4.z);
    whl[3][t] = __float2half(-2.f * w4.w);
    float4 ws = w4;
#pragma unroll
    for (int off = 32; off > 0; off >>= 1) {
      ws.x += __shfl_down(ws.x, off, 64);
      ws.y += __shfl_down(ws.y, off, 64);
      ws.z += __shfl_down(ws.z, off, 64);
      ws.w += __shfl_down(ws.w, off, 64);
    }
    if ((t & 63) == 0) wpart[t >> 6] = ws;
  }
  H8 z;
  z.p[0] = z.p[1] = z.p[2] = z.p[3] = __floats2half2_rn(0.f, 0.f);
  for (int p = t; p < 1024; p += 256) {   // 64 rows x 16 b128 segments
    int r = p >> 4, seg = (p & 15) * 8;
    if (r < 32) {
      int i = ib + r;
      H8 v = z;
      if (i >= 0 && i < LDIM) v = *(const H8*)&hid[((size_t)(b * LDIM + i)) * HDIM + seg];
      *(H8*)&rl[r][seg] = v;
    } else {
      int j = jb + (r - 32);
      H8 v = z;
      if (j >= 0 && j < LDIM) v = *(const H8*)&hid[((size_t)((BDIM + b) * LDIM + j)) * HDIM + seg];
      *(H8*)&ll[r - 32][seg] = v;
    }
  }
  __syncthreads();
  float4 wp0 = wpart[0], wp1 = wpart[1];
  const float4 wsum = make_float4(wp0.x + wp1.x, wp0.y + wp1.y,
                                  wp0.z + wp1.z, wp0.w + wp1.w);

  // phase B: thread = one ii row x 4 jj cols (jlo, +8, +16, +24)
  const int ii = t >> 3;
  const int jlo = t & 7;
  const __half2 one2 = __float2half2_rn(1.0f);
  __half2 aE[4][4], aO[4][4];
#pragma unroll
  for (int q = 0; q < 4; ++q)
#pragma unroll
    for (int k = 0; k < 4; ++k) {
      aE[q][k] = __float2half2_rn(0.f);
      aO[q][k] = __float2half2_rn(0.f);
    }

#define DO_JJ(Q, JJ)                                                          \
  {                                                                           \
    H8 l8 = *(const H8*)&ll[(JJ)][h];                                         \
    __half2 g0 = h2rcp(__hadd2(h2exp2(__hmul2(r8.p[0], l8.p[0])), one2));     \
    __half2 g1 = h2rcp(__hadd2(h2exp2(__hmul2(r8.p[1], l8.p[1])), one2));     \
    __half2 g2 = h2rcp(__hadd2(h2exp2(__hmul2(r8.p[2], l8.p[2])), one2));     \
    __half2 g3 = h2rcp(__hadd2(h2exp2(__hmul2(r8.p[3], l8.p[3])), one2));     \
    _Pragma("unroll")                                                         \
    for (int k = 0; k < 4; ++k) {                                             \
      aE[Q][k] = __hfma2(g0, wk[k].p[0], aE[Q][k]);                           \
      aE[Q][k] = __hfma2(g1, wk[k].p[1], aE[Q][k]);                           \
      aO[Q][k] = __hfma2(g2, wk[k].p[2], aO[Q][k]);                           \
      aO[Q][k] = __hfma2(g3, wk[k].p[3], aO[Q][k]);                           \
    }                                                                         \
  }

  for (int h = 0; h < HDIM; h += 8) {
    H8 r8 = *(const H8*)&rl[ii][h];
    H8 wk[4];
#pragma unroll
    for (int k = 0; k < 4; ++k) wk[k] = *(const H8*)&whl[k][h];
    DO_JJ(0, jlo)
    DO_JJ(1, jlo + 8)
    DO_JJ(2, jlo + 16)
    DO_JJ(3, jlo + 24)
  }
#undef DO_JJ

#pragma unroll
  for (int q = 0; q < 4; ++q) {
    float4 s;
    s.x = wsum.x + sum_h2(aE[q][0]) + sum_h2(aO[q][0]);
    s.y = wsum.y + sum_h2(aE[q][1]) + sum_h2(aO[q][1]);
    s.z = wsum.z + sum_h2(aE[q][2]) + sum_h2(aO[q][2]);
    s.w = wsum.w + sum_h2(aE[q][3]) + sum_h2(aO[q][3]);
    sl[ii][jlo + q * 8] = s;
  }
  __syncthreads();

  // phase C: y[i,j] = cb + s00(i-1,j-1)+s01(i-1,j)+s10(i,j-1)+s11(i,j); max
  float m = -INFINITY;
  const float cbv = cb[0];
  for (int p = t; p < 1024; p += 256) {
    int jj = p & 31, iy = p >> 5;
    int i = ib + iy, j = jb + jj;
    if (iy > 0 && jj > 0 && i < LDIM && j < LDIM) {
      float v = cbv + sl[iy - 1][jj - 1].x + sl[iy - 1][jj].y
                    + sl[iy][jj - 1].z + sl[iy][jj].w;
      m = fmaxf(m, v);
    }
  }
#pragma unroll
  for (int off = 32; off > 0; off >>= 1) m = fmaxf(m, __shfl_down(m, off, 64));
  if ((t & 63) == 0) wred[t >> 6] = m;
  __syncthreads();

  // tail: write partial, count, last block reduces + sigmoid.
  if (t == 0) {
    float mm = fmaxf(fmaxf(wred[0], wred[1]), fmaxf(wred[2], wred[3]));
    partial[((size_t)b * NT + blockIdx.y) * NT + blockIdx.x] = mm;
    __threadfence();                       // partial visible device-wide
    unsigned old = atomicAdd(ctr, 1u);     // device-scope
    slast = (old == NTILES - 1) ? 1u : 0u;
  }
  __syncthreads();
  if (slast) {
    __threadfence();
    const int wv = t >> 6, ln = t & 63;    // wave wv reduces batch wv
    float mm = -INFINITY;
    for (int p = ln; p < NT * NT; p += 64) {
      float v = __hip_atomic_load(&partial[wv * NT * NT + p],
                                  __ATOMIC_RELAXED, __HIP_MEMORY_SCOPE_AGENT);
      mm = fmaxf(mm, v);
    }
#pragma unroll
    for (int off = 32; off > 0; off >>= 1) mm = fmaxf(mm, __shfl_down(mm, off, 64));
    if (ln == 0) out[wv] = 1.f / (1.f + expf(-mm));
  }
}

extern "C" void kernel_launch(void* const* d_in, const int* in_sizes, int n_in,
                              void* d_out, int out_size, void* d_ws, size_t ws_size,
                              hipStream_t stream) {
  const float* rec = (const float*)d_in[0];
  const float* lig = (const float*)d_in[1];
  const float* W1  = (const float*)d_in[2];
  const float* b1  = (const float*)d_in[3];
  const float* cw  = (const float*)d_in[4];   // (1,H,2,2) = float4 per h
  const float* cb  = (const float*)d_in[5];
  float* out = (float*)d_out;

  ushort_t* Wt   = (ushort_t*)d_ws;                       // 128x1024 f16 = 256 KB
  ushort_t* hid  = Wt + (size_t)HDIM * EDIM;              // 4096x128 f16 = 1 MB
  float* partial = (float*)(hid + (size_t)2 * BDIM * LDIM * HDIM);  // 1156 f32
  unsigned* ctr  = (unsigned*)(partial + NTILES);

  cvt<<<dim3(64), 256, 0, stream>>>(W1, Wt, ctr);
  gemm_direct<<<dim3(512), 256, 0, stream>>>(rec, lig, Wt, b1, hid);
  bilinear_max<<<dim3(NT, NT, BDIM), 256, 0, stream>>>(hid, (const float4*)cw, cb,
                                                       partial, ctr, out);
}

// Round 10
// 141.573 us; speedup vs baseline: 1.0509x; 1.0509x over previous
//
#include <hip/hip_runtime.h>
#include <hip/hip_fp16.h>
#include <math.h>

#define BDIM 4
#define LDIM 512
#define EDIM 1024
#define HDIM 128
#define TILE 31            // interior y-tile per block (s-grid is 32x32 with 1 halo)
#define NT   17            // 17*31 = 527 >= 512 tiles per spatial dim
#define K2   2.885390081777927f   // 2/ln(2)

typedef unsigned short ushort_t;
typedef __attribute__((ext_vector_type(8))) _Float16 half8;
typedef __attribute__((ext_vector_type(4))) float f32x4;

struct __align__(16) H8 { __half2 p[4]; };
union HU { H8 h; half8 v; };

__device__ __forceinline__ float sum_h2(__half2 v) {
  return __low2float(v) + __high2float(v);
}

// ---------------------------------------------------------------------------
// Kernel 0: W1 (1024x128 f32, k-major) -> Wt (128x1024 f16, n-major, k-contig)
// ---------------------------------------------------------------------------
__global__ __launch_bounds__(256) void wcvt(const float* __restrict__ W1,
                                            ushort_t* __restrict__ Wt) {
  const int g = (int)blockIdx.x * 256 + threadIdx.x;  // 0..16383
  const int n = g & 127, k8 = g >> 7;                 // k8: 0..127
  float v[8];
#pragma unroll
  for (int j = 0; j < 8; ++j) v[j] = W1[(size_t)(k8 * 8 + j) * HDIM + n];
  H8 o;
#pragma unroll
  for (int j = 0; j < 4; ++j) o.p[j] = __floats2half2_rn(v[2 * j], v[2 * j + 1]);
  *(H8*)&Wt[(size_t)n * EDIM + k8 * 8] = o;
}

// ---------------------------------------------------------------------------
// Kernel 1: hid = relu(emb @ W1 + b1), f16 out; rec rows scaled by -K2 so the
// bilinear kernel's exp2 argument is just r*l. NO LDS / barriers / atomics:
// 2048 independent waves; wave = 16-row strip x one 16-col frag x full K.
// ---------------------------------------------------------------------------
__global__ __launch_bounds__(256) void gemm_direct(
    const float* __restrict__ rec, const float* __restrict__ lig,
    const ushort_t* __restrict__ Wt, const float* __restrict__ b1,
    ushort_t* __restrict__ hid) {
  const int gw = (int)blockIdx.x * 4 + (threadIdx.x >> 6);  // 0..2047
  const int l = threadIdx.x & 63;
  const int strip = gw >> 3;          // 0..255 -> rows strip*16..+15
  const int nidx = gw & 7;            // col frag: cols nidx*16..+15
  const int r0 = strip * 16;
  const int m = l & 15, q = l >> 4;   // frag row, k-octet quad
  const float* arow = ((r0 < BDIM * LDIM)
                           ? rec + (size_t)r0 * EDIM
                           : lig + (size_t)(r0 - BDIM * LDIM) * EDIM) +
                      (size_t)m * EDIM + q * 8;
  const ushort_t* brow = Wt + (size_t)(nidx * 16 + m) * EDIM + q * 8;

  f32x4 acc = {0.f, 0.f, 0.f, 0.f};
#pragma unroll 8
  for (int c = 0; c < 32; ++c) {
    const int k0 = c * 32;
    float4 a_lo = *(const float4*)(arow + k0);
    float4 a_hi = *(const float4*)(arow + k0 + 4);
    HU au;
    au.h.p[0] = __floats2half2_rn(a_lo.x, a_lo.y);
    au.h.p[1] = __floats2half2_rn(a_lo.z, a_lo.w);
    au.h.p[2] = __floats2half2_rn(a_hi.x, a_hi.y);
    au.h.p[3] = __floats2half2_rn(a_hi.z, a_hi.w);
    half8 bf = *(const half8*)(brow + k0);
    acc = __builtin_amdgcn_mfma_f32_16x16x32_f16(au.v, bf, acc, 0, 0, 0);
  }

  // C/D: col(n) = lane&15, row(m) = (lane>>4)*4 + reg  [validated rounds 4-9]
  const float scale = (r0 < BDIM * LDIM) ? -K2 : 1.0f;   // NOTE: minus K2
  const int col = nidx * 16 + m;
  const float bias = b1[col];
#pragma unroll
  for (int r = 0; r < 4; ++r) {
    float v = fmaxf(acc[r] + bias, 0.f) * scale;
    ((_Float16*)hid)[(size_t)(r0 + q * 4 + r) * HDIM + col] = (_Float16)v;
  }
}

// ---------------------------------------------------------------------------
// Kernel 2 (R5 core + polynomial G): per 31x31 y-tile:
//   s_k(p,q) = Wsum_k + sum_h (-2 w_k[h]) * G(p,q,h)
//   G = 1/(1+2^{K2 x}) = u/(1+u),  u = 2^{-K2 x} = exp2(r'*l)  (r' = -K2 r)
//   u/(1+u) ~= u*(B1 + u*(B2 + u*(B3 + u*(B4 + u*B5))))  on u in [0,1]
//   (Chebyshev-derived, |err| <= ~1e-4 before f16 rounding; no rcp, no inf)
// ---------------------------------------------------------------------------
__global__ __launch_bounds__(256, 4) void bilinear_max(
    const ushort_t* __restrict__ hid, const float4* __restrict__ cw4,
    const float* __restrict__ cb, float* __restrict__ partial) {
  __shared__ ushort_t rl[32][136];   // 272 B row stride
  __shared__ ushort_t ll[32][136];
  __shared__ __half whl[4][HDIM];    // -2*w_k[h] as f16, h-contiguous
  __shared__ float4 sl[32][33];      // f32 taps
  __shared__ float wred[4];
  __shared__ float4 wpart[2];

  const int t = threadIdx.x;
  const int b = blockIdx.z;
  const int ib = (int)blockIdx.y * TILE - 1;
  const int jb = (int)blockIdx.x * TILE - 1;

  if (t < HDIM) {
    float4 w4 = cw4[t];
    whl[0][t] = __float2half(-2.f * w4.x);
    whl[1][t] = __float2half(-2.f * w4.y);
    whl[2][t] = __float2half(-2.f * w4.z);
    whl[3][t] = __float2half(-2.f * w4.w);
    float4 ws = w4;
#pragma unroll
    for (int off = 32; off > 0; off >>= 1) {
      ws.x += __shfl_down(ws.x, off, 64);
      ws.y += __shfl_down(ws.y, off, 64);
      ws.z += __shfl_down(ws.z, off, 64);
      ws.w += __shfl_down(ws.w, off, 64);
    }
    if ((t & 63) == 0) wpart[t >> 6] = ws;
  }
  H8 z;
  z.p[0] = z.p[1] = z.p[2] = z.p[3] = __floats2half2_rn(0.f, 0.f);
  for (int p = t; p < 1024; p += 256) {   // 64 rows x 16 b128 segments
    int r = p >> 4, seg = (p & 15) * 8;
    if (r < 32) {
      int i = ib + r;
      H8 v = z;
      if (i >= 0 && i < LDIM) v = *(const H8*)&hid[((size_t)(b * LDIM + i)) * HDIM + seg];
      *(H8*)&rl[r][seg] = v;
    } else {
      int j = jb + (r - 32);
      H8 v = z;
      if (j >= 0 && j < LDIM) v = *(const H8*)&hid[((size_t)((BDIM + b) * LDIM + j)) * HDIM + seg];
      *(H8*)&ll[r - 32][seg] = v;
    }
  }
  __syncthreads();
  float4 wp0 = wpart[0], wp1 = wpart[1];
  const float4 wsum = make_float4(wp0.x + wp1.x, wp0.y + wp1.y,
                                  wp0.z + wp1.z, wp0.w + wp1.w);

  // phase B: thread = one ii row x 4 jj cols (jlo, +8, +16, +24)
  const int ii = t >> 3;
  const int jlo = t & 7;
  const __half2 B1 = __float2half2_rn(0.996640f);
  const __half2 B2 = __float2half2_rn(-0.956096f);
  const __half2 B3 = __float2half2_rn(0.777795f);
  const __half2 B4 = __float2half2_rn(-0.426008f);
  const __half2 B5 = __float2half2_rn(0.107657f);
  __half2 aE[4][4], aO[4][4];
#pragma unroll
  for (int q = 0; q < 4; ++q)
#pragma unroll
    for (int k = 0; k < 4; ++k) {
      aE[q][k] = __float2half2_rn(0.f);
      aO[q][k] = __float2half2_rn(0.f);
    }

#define POLYG(U) \
  __hmul2(U, __hfma2(U, __hfma2(U, __hfma2(U, __hfma2(U, B5, B4), B3), B2), B1))
#define DO_JJ(Q, JJ)                                                          \
  {                                                                           \
    H8 l8 = *(const H8*)&ll[(JJ)][h];                                         \
    __half2 u0 = h2exp2(__hmul2(r8.p[0], l8.p[0]));                           \
    __half2 u1 = h2exp2(__hmul2(r8.p[1], l8.p[1]));                           \
    __half2 u2 = h2exp2(__hmul2(r8.p[2], l8.p[2]));                           \
    __half2 u3 = h2exp2(__hmul2(r8.p[3], l8.p[3]));                           \
    __half2 g0 = POLYG(u0);                                                   \
    __half2 g1 = POLYG(u1);                                                   \
    __half2 g2 = POLYG(u2);                                                   \
    __half2 g3 = POLYG(u3);                                                   \
    _Pragma("unroll")                                                         \
    for (int k = 0; k < 4; ++k) {                                             \
      aE[Q][k] = __hfma2(g0, wk[k].p[0], aE[Q][k]);                           \
      aE[Q][k] = __hfma2(g1, wk[k].p[1], aE[Q][k]);                           \
      aO[Q][k] = __hfma2(g2, wk[k].p[2], aO[Q][k]);                           \
      aO[Q][k] = __hfma2(g3, wk[k].p[3], aO[Q][k]);                           \
    }                                                                         \
  }

  for (int h = 0; h < HDIM; h += 8) {
    H8 r8 = *(const H8*)&rl[ii][h];
    H8 wk[4];
#pragma unroll
    for (int k = 0; k < 4; ++k) wk[k] = *(const H8*)&whl[k][h];
    DO_JJ(0, jlo)
    DO_JJ(1, jlo + 8)
    DO_JJ(2, jlo + 16)
    DO_JJ(3, jlo + 24)
  }
#undef DO_JJ
#undef POLYG

#pragma unroll
  for (int q = 0; q < 4; ++q) {
    float4 s;
    s.x = wsum.x + sum_h2(aE[q][0]) + sum_h2(aO[q][0]);
    s.y = wsum.y + sum_h2(aE[q][1]) + sum_h2(aO[q][1]);
    s.z = wsum.z + sum_h2(aE[q][2]) + sum_h2(aO[q][2]);
    s.w = wsum.w + sum_h2(aE[q][3]) + sum_h2(aO[q][3]);
    sl[ii][jlo + q * 8] = s;
  }
  __syncthreads();

  // phase C: y[i,j] = cb + s00(i-1,j-1)+s01(i-1,j)+s10(i,j-1)+s11(i,j); max
  float m = -INFINITY;
  const float cbv = cb[0];
  for (int p = t; p < 1024; p += 256) {
    int jj = p & 31, iy = p >> 5;
    int i = ib + iy, j = jb + jj;
    if (iy > 0 && jj > 0 && i < LDIM && j < LDIM) {
      float v = cbv + sl[iy - 1][jj - 1].x + sl[iy - 1][jj].y
                    + sl[iy][jj - 1].z + sl[iy][jj].w;
      m = fmaxf(m, v);
    }
  }
#pragma unroll
  for (int off = 32; off > 0; off >>= 1) m = fmaxf(m, __shfl_down(m, off, 64));
  if ((t & 63) == 0) wred[t >> 6] = m;
  __syncthreads();
  if (t == 0) {
    float mm = fmaxf(fmaxf(wred[0], wred[1]), fmaxf(wred[2], wred[3]));
    partial[((size_t)b * NT + blockIdx.y) * NT + blockIdx.x] = mm;
  }
}

// ---------------------------------------------------------------------------
// Kernel 3: reduce 17x17 partials per batch, sigmoid, write 4 outputs.
// ---------------------------------------------------------------------------
__global__ __launch_bounds__(64) void finalize(const float* __restrict__ partial,
                                               float* __restrict__ out) {
  const int b = blockIdx.x, t = threadIdx.x;
  float m = -INFINITY;
  for (int p = t; p < NT * NT; p += 64) m = fmaxf(m, partial[b * NT * NT + p]);
#pragma unroll
  for (int off = 32; off > 0; off >>= 1) m = fmaxf(m, __shfl_down(m, off, 64));
  if (t == 0) out[b] = 1.f / (1.f + expf(-m));
}

extern "C" void kernel_launch(void* const* d_in, const int* in_sizes, int n_in,
                              void* d_out, int out_size, void* d_ws, size_t ws_size,
                              hipStream_t stream) {
  const float* rec = (const float*)d_in[0];
  const float* lig = (const float*)d_in[1];
  const float* W1  = (const float*)d_in[2];
  const float* b1  = (const float*)d_in[3];
  const float* cw  = (const float*)d_in[4];   // (1,H,2,2) = float4 per h
  const float* cb  = (const float*)d_in[5];
  float* out = (float*)d_out;

  ushort_t* Wt   = (ushort_t*)d_ws;                       // 128x1024 f16 = 256 KB
  ushort_t* hid  = Wt + (size_t)HDIM * EDIM;              // 4096x128 f16 = 1 MB
  float* partial = (float*)(hid + (size_t)2 * BDIM * LDIM * HDIM);  // 1156 f32

  wcvt<<<dim3(64), 256, 0, stream>>>(W1, Wt);
  gemm_direct<<<dim3(512), 256, 0, stream>>>(rec, lig, Wt, b1, hid);
  bilinear_max<<<dim3(NT, NT, BDIM), 256, 0, stream>>>(hid, (const float4*)cw, cb, partial);
  finalize<<<dim3(BDIM), 64, 0, stream>>>(partial, out);
}

// Round 11
// 131.345 us; speedup vs baseline: 1.1328x; 1.0779x over previous
//
#include <hip/hip_runtime.h>
#include <hip/hip_fp16.h>
#include <math.h>

#define BDIM 4
#define LDIM 512
#define EDIM 1024
#define HDIM 128
#define TILE 31            // interior y-tile per block (s-grid is 32x32 with 1 halo)
#define NT   17            // 17*31 = 527 >= 512 tiles per spatial dim
#define K2   2.885390081777927f   // 2/ln(2)

typedef unsigned short ushort_t;
typedef __attribute__((ext_vector_type(8))) _Float16 half8;
typedef __attribute__((ext_vector_type(4))) float f32x4;

struct __align__(16) H8 { __half2 p[4]; };
union HU { H8 h; half8 v; };

// ---------------------------------------------------------------------------
// Kernel 0: W1 (1024x128 f32, k-major) -> Wt (128x1024 f16, n-major, k-contig)
// ---------------------------------------------------------------------------
__global__ __launch_bounds__(256) void wcvt(const float* __restrict__ W1,
                                            ushort_t* __restrict__ Wt) {
  const int g = (int)blockIdx.x * 256 + threadIdx.x;  // 0..16383
  const int n = g & 127, k8 = g >> 7;                 // k8: 0..127
  float v[8];
#pragma unroll
  for (int j = 0; j < 8; ++j) v[j] = W1[(size_t)(k8 * 8 + j) * HDIM + n];
  H8 o;
#pragma unroll
  for (int j = 0; j < 4; ++j) o.p[j] = __floats2half2_rn(v[2 * j], v[2 * j + 1]);
  *(H8*)&Wt[(size_t)n * EDIM + k8 * 8] = o;
}

// ---------------------------------------------------------------------------
// Kernel 1: hid = relu(emb @ W1 + b1), f16 out; rec rows scaled by -K2 so
// the bilinear exp2 argument is just r*l (u in (0,1]). No LDS/barriers.
// 4-deep register load pipeline (R10's VGPR=12 build exposed full load
// latency every chunk; batching 4 chunks of loads cuts rounds 32 -> 8).
// ---------------------------------------------------------------------------
__global__ __launch_bounds__(256) void gemm_direct(
    const float* __restrict__ rec, const float* __restrict__ lig,
    const ushort_t* __restrict__ Wt, const float* __restrict__ b1,
    ushort_t* __restrict__ hid) {
  const int gw = (int)blockIdx.x * 4 + (threadIdx.x >> 6);  // 0..2047
  const int l = threadIdx.x & 63;
  const int strip = gw >> 3;          // rows strip*16..+15
  const int nidx = gw & 7;            // cols nidx*16..+15
  const int r0 = strip * 16;
  const int m = l & 15, q = l >> 4;
  const float* arow = ((r0 < BDIM * LDIM)
                           ? rec + (size_t)r0 * EDIM
                           : lig + (size_t)(r0 - BDIM * LDIM) * EDIM) +
                      (size_t)m * EDIM + q * 8;
  const ushort_t* brow = Wt + (size_t)(nidx * 16 + m) * EDIM + q * 8;

  f32x4 acc = {0.f, 0.f, 0.f, 0.f};
  for (int blk = 0; blk < 8; ++blk) {
    float4 alo[4], ahi[4];
    half8 bf[4];
#pragma unroll
    for (int j = 0; j < 4; ++j) {
      const int k0 = (blk * 4 + j) * 32;
      alo[j] = *(const float4*)(arow + k0);
      ahi[j] = *(const float4*)(arow + k0 + 4);
      bf[j] = *(const half8*)(brow + k0);
    }
#pragma unroll
    for (int j = 0; j < 4; ++j) {
      HU au;
      au.h.p[0] = __floats2half2_rn(alo[j].x, alo[j].y);
      au.h.p[1] = __floats2half2_rn(alo[j].z, alo[j].w);
      au.h.p[2] = __floats2half2_rn(ahi[j].x, ahi[j].y);
      au.h.p[3] = __floats2half2_rn(ahi[j].z, ahi[j].w);
      acc = __builtin_amdgcn_mfma_f32_16x16x32_f16(au.v, bf[j], acc, 0, 0, 0);
    }
  }

  // C/D: col(n) = lane&15, row(m) = (lane>>4)*4 + reg  [validated R4-R10]
  const float scale = (r0 < BDIM * LDIM) ? -K2 : 1.0f;   // minus K2
  const int col = nidx * 16 + m;
  const float bias = b1[col];
#pragma unroll
  for (int r = 0; r < 4; ++r) {
    float v = fmaxf(acc[r] + bias, 0.f) * scale;
    ((_Float16*)hid)[(size_t)(r0 + q * 4 + r) * HDIM + col] = (_Float16)v;
  }
}

// ---------------------------------------------------------------------------
// Kernel 2: per 31x31 y-tile. s_k(p,q) = Wsum_k + sum_h (-2 w_k[h])*G(p,q,h),
// G = u*P3(u), u = exp2(r'*l) in (0,1]  (r' = -K2*r; deg-3 Chebyshev of
// 1/(1+u), |err|<=~1e-3). Tap reduction over h done by MFMA 16x16x32:
// A-frag = G (lane&15 = pair m), B-frag = -2w (cols 0..3 = taps, rest 0),
// 4 chained MFMAs cover h=128. Wave w: 16 groups (ii, jj half-row).
// ---------------------------------------------------------------------------
__global__ __launch_bounds__(256, 4) void bilinear_max(
    const ushort_t* __restrict__ hid, const float* __restrict__ cw,
    const float* __restrict__ cb, float* __restrict__ partial) {
  __shared__ ushort_t rl[32][136];   // 272 B row stride
  __shared__ ushort_t ll[32][136];
  __shared__ float4 sl[32][33];      // f32 taps per (p,q)
  __shared__ float wred[4];
  __shared__ float wpart[2][4];

  const int t = threadIdx.x;
  const int b = blockIdx.z;
  const int ib = (int)blockIdx.y * TILE - 1;
  const int jb = (int)blockIdx.x * TILE - 1;
  const int w = t >> 6, l = t & 63;
  const int q = l >> 4, c15 = l & 15;

  // wsum_k = sum_h w_k[h]: threads 0..127 reduce (2 waves)
  if (t < HDIM) {
    float4 w4 = *(const float4*)&cw[t * 4];
#pragma unroll
    for (int off = 32; off > 0; off >>= 1) {
      w4.x += __shfl_down(w4.x, off, 64);
      w4.y += __shfl_down(w4.y, off, 64);
      w4.z += __shfl_down(w4.z, off, 64);
      w4.w += __shfl_down(w4.w, off, 64);
    }
    if ((t & 63) == 0) {
      wpart[t >> 6][0] = w4.x; wpart[t >> 6][1] = w4.y;
      wpart[t >> 6][2] = w4.z; wpart[t >> 6][3] = w4.w;
    }
  }

  // B-frag: -2*w_tap for tap = c15 (cols >= 4 zero), per 32-h chunk c.
  half8 wf[4];
#pragma unroll
  for (int c = 0; c < 4; ++c) {
#pragma unroll
    for (int j = 0; j < 8; ++j) {
      float v = (c15 < 4) ? cw[(size_t)(c * 32 + q * 8 + j) * 4 + c15] : 0.f;
      wf[c][j] = (_Float16)(-2.f * v);
    }
  }

  // stage tiles
  H8 z;
  z.p[0] = z.p[1] = z.p[2] = z.p[3] = __floats2half2_rn(0.f, 0.f);
  for (int p = t; p < 1024; p += 256) {   // 64 rows x 16 b128 segments
    int r = p >> 4, seg = (p & 15) * 8;
    if (r < 32) {
      int i = ib + r;
      H8 v = z;
      if (i >= 0 && i < LDIM) v = *(const H8*)&hid[((size_t)(b * LDIM + i)) * HDIM + seg];
      *(H8*)&rl[r][seg] = v;
    } else {
      int j = jb + (r - 32);
      H8 v = z;
      if (j >= 0 && j < LDIM) v = *(const H8*)&hid[((size_t)((BDIM + b) * LDIM + j)) * HDIM + seg];
      *(H8*)&ll[r - 32][seg] = v;
    }
  }
  __syncthreads();
  const float wsum_v = (c15 < 4) ? (wpart[0][c15] + wpart[1][c15]) : 0.f;

  // phase B: wave w covers ii in [8w, 8w+8); group g -> (ii, jj half)
  const __half2 D0 = __float2half2_rn(0.998539f);
  const __half2 D1 = __float2half2_rn(-0.947090f);
  const __half2 D2 = __float2half2_rn(0.676154f);
  const __half2 D3 = __float2half2_rn(-0.228646f);

#define POLYG(U) \
  __hmul2(U, __hfma2(U, __hfma2(U, __hfma2(U, D3, D2), D1), D0))

  for (int g = 0; g < 16; ++g) {
    const int ii = w * 8 + (g >> 1);
    const int jj0 = (g & 1) << 4;
    f32x4 acc = {0.f, 0.f, 0.f, 0.f};
#pragma unroll
    for (int c = 0; c < 4; ++c) {
      HU ru, lu, gu;
      ru.v = *(const half8*)&rl[ii][c * 32 + q * 8];          // broadcast in quad
      lu.v = *(const half8*)&ll[jj0 + c15][c * 32 + q * 8];
      __half2 u0 = h2exp2(__hmul2(ru.h.p[0], lu.h.p[0]));
      __half2 u1 = h2exp2(__hmul2(ru.h.p[1], lu.h.p[1]));
      __half2 u2 = h2exp2(__hmul2(ru.h.p[2], lu.h.p[2]));
      __half2 u3 = h2exp2(__hmul2(ru.h.p[3], lu.h.p[3]));
      gu.h.p[0] = POLYG(u0);
      gu.h.p[1] = POLYG(u1);
      gu.h.p[2] = POLYG(u2);
      gu.h.p[3] = POLYG(u3);
      acc = __builtin_amdgcn_mfma_f32_16x16x32_f16(gu.v, wf[c], acc, 0, 0, 0);
    }
    // D: col = lane&15 = tap, row = q*4+reg = pair (jj offset)
    if (c15 < 4) {
#pragma unroll
      for (int r = 0; r < 4; ++r)
        ((float*)&sl[ii][jj0 + q * 4 + r])[c15] = wsum_v + acc[r];
    }
  }
#undef POLYG
  __syncthreads();

  // phase C: y[i,j] = cb + s00(i-1,j-1)+s01(i-1,j)+s10(i,j-1)+s11(i,j); max
  float m = -INFINITY;
  const float cbv = cb[0];
  for (int p = t; p < 1024; p += 256) {
    int jj = p & 31, iy = p >> 5;
    int i = ib + iy, j = jb + jj;
    if (iy > 0 && jj > 0 && i < LDIM && j < LDIM) {
      float v = cbv + sl[iy - 1][jj - 1].x + sl[iy - 1][jj].y
                    + sl[iy][jj - 1].z + sl[iy][jj].w;
      m = fmaxf(m, v);
    }
  }
#pragma unroll
  for (int off = 32; off > 0; off >>= 1) m = fmaxf(m, __shfl_down(m, off, 64));
  if ((t & 63) == 0) wred[t >> 6] = m;
  __syncthreads();
  if (t == 0) {
    float mm = fmaxf(fmaxf(wred[0], wred[1]), fmaxf(wred[2], wred[3]));
    partial[((size_t)b * NT + blockIdx.y) * NT + blockIdx.x] = mm;
  }
}

// ---------------------------------------------------------------------------
// Kernel 3: reduce 17x17 partials per batch, sigmoid, write 4 outputs.
// ---------------------------------------------------------------------------
__global__ __launch_bounds__(64) void finalize(const float* __restrict__ partial,
                                               float* __restrict__ out) {
  const int b = blockIdx.x, t = threadIdx.x;
  float m = -INFINITY;
  for (int p = t; p < NT * NT; p += 64) m = fmaxf(m, partial[b * NT * NT + p]);
#pragma unroll
  for (int off = 32; off > 0; off >>= 1) m = fmaxf(m, __shfl_down(m, off, 64));
  if (t == 0) out[b] = 1.f / (1.f + expf(-m));
}

extern "C" void kernel_launch(void* const* d_in, const int* in_sizes, int n_in,
                              void* d_out, int out_size, void* d_ws, size_t ws_size,
                              hipStream_t stream) {
  const float* rec = (const float*)d_in[0];
  const float* lig = (const float*)d_in[1];
  const float* W1  = (const float*)d_in[2];
  const float* b1  = (const float*)d_in[3];
  const float* cw  = (const float*)d_in[4];   // (1,H,2,2): float4 {w00,w01,w10,w11} per h
  const float* cb  = (const float*)d_in[5];
  float* out = (float*)d_out;

  ushort_t* Wt   = (ushort_t*)d_ws;                       // 128x1024 f16 = 256 KB
  ushort_t* hid  = Wt + (size_t)HDIM * EDIM;              // 4096x128 f16 = 1 MB
  float* partial = (float*)(hid + (size_t)2 * BDIM * LDIM * HDIM);  // 1156 f32

  wcvt<<<dim3(64), 256, 0, stream>>>(W1, Wt);
  gemm_direct<<<dim3(512), 256, 0, stream>>>(rec, lig, Wt, b1, hid);
  bilinear_max<<<dim3(NT, NT, BDIM), 256, 0, stream>>>(hid, cw, cb, partial);
  finalize<<<dim3(BDIM), 64, 0, stream>>>(partial, out);
}